// Round 3
// baseline (333.781 us; speedup 1.0000x reference)
//
#include <hip/hip_runtime.h>

#define NB 4
#define NCH 256
#define NTOK 4096

typedef _Float16 f16x4 __attribute__((ext_vector_type(4)));
typedef _Float16 f16x8 __attribute__((ext_vector_type(8)));
typedef __fp16 h16x2 __attribute__((ext_vector_type(2)));
typedef float f32x4 __attribute__((ext_vector_type(4)));

union I4F16 { int i[4]; f16x8 v; };
union F2H  { h16x2 h; int i; };

// ---------------- K0: pack Wq/Wk/Wv -> fp16 [320][256] ----------------
__global__ __launch_bounds__(256) void wpack_kernel(
    const float* __restrict__ Wq, const float* __restrict__ Wk,
    const float* __restrict__ Wv, _Float16* __restrict__ W16)
{
    int g = blockIdx.x * 256 + threadIdx.x;       // 80 blocks -> 20480 quads
    if (g >= 320 * 64) return;
    int o = g >> 6, c4 = g & 63;
    const float* src = (o < 32) ? (Wq + o * NCH) :
                       (o < 64) ? (Wk + (o - 32) * NCH) : (Wv + (o - 64) * NCH);
    float4 v = ((const float4*)src)[c4];
    f16x4 p;
    p[0] = (_Float16)v.x; p[1] = (_Float16)v.y;
    p[2] = (_Float16)v.z; p[3] = (_Float16)v.w;
    *(f16x4*)(W16 + (size_t)o * NCH + c4 * 4) = p;
}

// ---------------- K1: QKV projection via MFMA ----------------
// Block: (b, 32-token tile). LDS: x-tile fp16 [32 n][256 c], XOR-swizzled.
// 4 waves x 5 o-tiles (o: 0-31 q, 32-63 k, 64-319 v), K=256 in 8 steps.
__global__ __launch_bounds__(256) void qkv_mfma_kernel(
    const float* __restrict__ x, const _Float16* __restrict__ W16,
    const float* __restrict__ bq, const float* __restrict__ bk,
    const float* __restrict__ bv,
    _Float16* __restrict__ qkT, _Float16* __restrict__ vbuf)
{
    __shared__ char xs[32 * 512];   // [n][c] f16, row 512B, swizzled
    const int tid = threadIdx.x;
    const int b = blockIdx.x & 3;
    const int n0 = (blockIdx.x >> 2) << 5;
    const float* xb = x + (size_t)b * NCH * NTOK + n0;

    // stage: thread t handles c-block c4 = t&63 (4 rows), n-oct no = t>>6 (8 cols)
    {
        const int c4 = tid & 63, no = tid >> 6;
        #pragma unroll
        for (int u = 0; u < 4; ++u) {
            const int c = c4 * 4 + u;
            const float* xr = xb + (size_t)c * NTOK + no * 8;
            float4 a = *(const float4*)(xr);
            float4 bvec = *(const float4*)(xr + 4);
            float vals[8] = {a.x,a.y,a.z,a.w,bvec.x,bvec.y,bvec.z,bvec.w};
            #pragma unroll
            for (int j = 0; j < 8; ++j) {
                const int n = no * 8 + j;
                *(_Float16*)(xs + n * 512 + ((c * 2) ^ ((n & 7) << 4))) = (_Float16)vals[j];
            }
        }
    }
    __syncthreads();

    const int w = tid >> 6, l = tid & 63;
    const int iofs = l & 15, h = l >> 4;

    f32x4 acc[5][2];
    #pragma unroll
    for (int ot = 0; ot < 5; ++ot)
        #pragma unroll
        for (int nt = 0; nt < 2; ++nt) acc[ot][nt] = (f32x4){0.f,0.f,0.f,0.f};

    #pragma unroll
    for (int kk = 0; kk < 8; ++kk) {
        I4F16 bf[2];
        #pragma unroll
        for (int nt = 0; nt < 2; ++nt) {
            const int n = nt * 16 + iofs;
            bf[nt].v = *(const f16x8*)(xs + n * 512 + ((kk * 64 + h * 16) ^ ((n & 7) << 4)));
        }
        #pragma unroll
        for (int ot = 0; ot < 5; ++ot) {
            const int og = w * 5 + ot;
            f16x8 af = *(const f16x8*)(W16 + (size_t)(og * 16 + iofs) * NCH + kk * 32 + h * 8);
            #pragma unroll
            for (int nt = 0; nt < 2; ++nt)
                acc[ot][nt] = __builtin_amdgcn_mfma_f32_16x16x32_f16(af, bf[nt].v, acc[ot][nt], 0, 0, 0);
        }
    }

    // epilogue: bias + stores. D: row o = og*16+4h+r, col n = n0+nt*16+iofs
    #pragma unroll
    for (int ot = 0; ot < 5; ++ot) {
        const int og = w * 5 + ot;
        float4 bias;
        if (og < 2)      bias = *(const float4*)(bq + og * 16 + 4 * h);
        else if (og < 4) bias = *(const float4*)(bk + (og - 2) * 16 + 4 * h);
        else             bias = *(const float4*)(bv + (og - 4) * 16 + 4 * h);
        #pragma unroll
        for (int nt = 0; nt < 2; ++nt) {
            const int n = n0 + nt * 16 + iofs;
            f32x4 a = acc[ot][nt];
            if (og < 4) {
                f16x4 pk;
                pk[0] = (_Float16)(a[0] + bias.x); pk[1] = (_Float16)(a[1] + bias.y);
                pk[2] = (_Float16)(a[2] + bias.z); pk[3] = (_Float16)(a[3] + bias.w);
                const int col = (og < 2) ? (og * 16 + 4 * h) : (32 + (og - 2) * 16 + 4 * h);
                *(f16x4*)(qkT + (size_t)(b * NTOK + n) * 64 + col) = pk;
            } else {
                const int ob = (og - 4) * 16 + 4 * h;
                const float bb[4] = {bias.x, bias.y, bias.z, bias.w};
                #pragma unroll
                for (int r = 0; r < 4; ++r)
                    vbuf[(size_t)(b * NCH + ob + r) * NTOK + n] = (_Float16)(a[r] + bb[r]);
            }
        }
    }
}

// ---------------- K2: softmax row-sums (1/sum of exp(energy)) ----------------
__global__ __launch_bounds__(256) void rowsum_kernel(
    const _Float16* __restrict__ qkT, float* __restrict__ rs_inv)
{
    const int b = blockIdx.x >> 6;
    const int i0 = (blockIdx.x & 63) << 6;
    const int tid = threadIdx.x;
    const int w = tid >> 6, l = tid & 63;
    const int lrow = l & 15, lgrp = l >> 4;
    const _Float16* base = qkT + (size_t)b * NTOK * 64;

    f16x8 qfrag = *(const f16x8*)(base + (size_t)(i0 + w*16 + lrow) * 64 + lgrp * 8);
    float sums[4] = {0.f, 0.f, 0.f, 0.f};
    const f32x4 zero = {0.f, 0.f, 0.f, 0.f};
    #pragma unroll 4
    for (int j0 = 0; j0 < NTOK; j0 += 16) {
        f16x8 kfrag = *(const f16x8*)(base + (size_t)(j0 + lrow) * 64 + 32 + lgrp * 8);
        f32x4 s = __builtin_amdgcn_mfma_f32_16x16x32_f16(qfrag, kfrag, zero, 0, 0, 0);
        #pragma unroll
        for (int r = 0; r < 4; ++r) sums[r] += __expf(s[r]);
    }
    #pragma unroll
    for (int m = 1; m < 16; m <<= 1) {
        #pragma unroll
        for (int r = 0; r < 4; ++r) sums[r] += __shfl_xor(sums[r], m, 64);
    }
    if (lrow == 0) {
        #pragma unroll
        for (int r = 0; r < 4; ++r)
            rs_inv[b * NTOK + i0 + w*16 + lgrp*4 + r] = 1.0f / sums[r];
    }
}

// ---------------- K3: fused energy -> softmax -> attention write -> PV ----------------
// Barrier-free, LDS-free. Each wave independent: 32 i-rows x 128 c-half.
// S computed transposed (mfma(k,q)): lane holds col i = l&15, rows j = h*4+r.
// P -> fp16 -> ds_bpermute exchange -> PV B-frag in-register.
__global__ __launch_bounds__(256, 1) void attn_pv_kernel(
    const _Float16* __restrict__ qkT, const _Float16* __restrict__ vbuf,
    const float* __restrict__ rs_inv, const float* __restrict__ x,
    const float* __restrict__ gamma, float* __restrict__ out, float* __restrict__ atn)
{
    const int tid = threadIdx.x;
    const int w = tid >> 6, l = tid & 63;
    const int iofs = l & 15, h = l >> 4;
    const int ch = blockIdx.x & 1;
    const int b = (blockIdx.x >> 1) & 3;
    const int it = ((blockIdx.x >> 3) << 2) | w;
    const int i0 = it << 5;          // 32 i-rows per wave
    const int c0 = ch << 7;          // 128-c half

    const _Float16* qk_b = qkT + (size_t)b * NTOK * 64;
    const _Float16* v_b  = vbuf + (size_t)b * NCH * NTOK;
    float* atn_b = atn + (size_t)b * NTOK * NTOK;

    f16x8 qfrag[2];
    float rsi[2];
    #pragma unroll
    for (int ig = 0; ig < 2; ++ig) {
        qfrag[ig] = *(const f16x8*)(qk_b + (size_t)(i0 + ig*16 + iofs) * 64 + h * 8);
        rsi[ig] = rs_inv[b * NTOK + i0 + ig*16 + iofs];
    }

    const f32x4 zero = {0.f, 0.f, 0.f, 0.f};
    f32x4 acc[2][8];
    #pragma unroll
    for (int ig = 0; ig < 2; ++ig)
        #pragma unroll
        for (int ct = 0; ct < 8; ++ct) acc[ig][ct] = zero;

    const int srcA = ((l & 15) << 2) | ((l & 16) << 3);   // lane (iofs, 2*(h&1)) * 4 bytes
    const int srcB = srcA + 64;
    const bool hi = (l >= 32);                            // t = h>>1

    for (int j0 = 0; j0 < NTOK; j0 += 32) {
        // S^T: 2 k-frags (j rows), per ig one mfma each
        f16x8 kfrag[2];
        #pragma unroll
        for (int t = 0; t < 2; ++t)
            kfrag[t] = *(const f16x8*)(qk_b + (size_t)(j0 + t*16 + iofs) * 64 + 32 + h * 8);

        I4F16 bfrag[2];
        #pragma unroll
        for (int ig = 0; ig < 2; ++ig) {
            int dw[2][2];
            #pragma unroll
            for (int t = 0; t < 2; ++t) {
                f32x4 s = __builtin_amdgcn_mfma_f32_16x16x32_f16(kfrag[t], qfrag[ig], zero, 0, 0, 0);
                float pvf[4];
                #pragma unroll
                for (int r = 0; r < 4; ++r) pvf[r] = __expf(s[r]) * rsi[ig];
                if (ch == 0) {
                    float4 st = {pvf[0], pvf[1], pvf[2], pvf[3]};
                    *(float4*)(atn_b + (size_t)(i0 + ig*16 + iofs) * NTOK + j0 + t*16 + h*4) = st;
                }
                F2H p0, p1;
                p0.h = __builtin_amdgcn_cvt_pkrtz(pvf[0], pvf[1]);
                p1.h = __builtin_amdgcn_cvt_pkrtz(pvf[2], pvf[3]);
                dw[t][0] = p0.i; dw[t][1] = p1.i;
            }
            // exchange: B-frag dword e2 <- lane (iofs, 2*(h&1)+(e2>>1)), reg dw[h>>1][e2&1]
            int a0 = __builtin_amdgcn_ds_bpermute(srcA, dw[0][0]);
            int a1 = __builtin_amdgcn_ds_bpermute(srcA, dw[1][0]);
            int b0 = __builtin_amdgcn_ds_bpermute(srcA, dw[0][1]);
            int b1 = __builtin_amdgcn_ds_bpermute(srcA, dw[1][1]);
            int c0_ = __builtin_amdgcn_ds_bpermute(srcB, dw[0][0]);
            int c1_ = __builtin_amdgcn_ds_bpermute(srcB, dw[1][0]);
            int d0 = __builtin_amdgcn_ds_bpermute(srcB, dw[0][1]);
            int d1 = __builtin_amdgcn_ds_bpermute(srcB, dw[1][1]);
            bfrag[ig].i[0] = hi ? a1 : a0;
            bfrag[ig].i[1] = hi ? b1 : b0;
            bfrag[ig].i[2] = hi ? c1_ : c0_;
            bfrag[ig].i[3] = hi ? d1 : d0;
        }
        // PV: v-frag shared across both i-groups
        #pragma unroll
        for (int ct = 0; ct < 8; ++ct) {
            f16x8 vfrag = *(const f16x8*)(v_b + (size_t)(c0 + ct*16 + iofs) * NTOK + j0 + h * 8);
            #pragma unroll
            for (int ig = 0; ig < 2; ++ig)
                acc[ig][ct] = __builtin_amdgcn_mfma_f32_16x16x32_f16(vfrag, bfrag[ig].v, acc[ig][ct], 0, 0, 0);
        }
    }

    // epilogue: out[b][c][i] = gamma*acc + x. D: row c-off = 4h+r, col i = iofs
    const float g = gamma[0];
    #pragma unroll
    for (int ig = 0; ig < 2; ++ig) {
        #pragma unroll
        for (int ct = 0; ct < 8; ++ct) {
            #pragma unroll
            for (int r = 0; r < 4; ++r) {
                const int c = c0 + ct*16 + 4*h + r;
                const size_t bse = ((size_t)(b * NCH + c)) * NTOK + i0 + ig*16 + iofs;
                out[bse] = g * acc[ig][ct][r] + x[bse];
            }
        }
    }
}

extern "C" void kernel_launch(void* const* d_in, const int* in_sizes, int n_in,
                              void* d_out, int out_size, void* d_ws, size_t ws_size,
                              hipStream_t stream) {
    const float* x     = (const float*)d_in[0];
    const float* Wq    = (const float*)d_in[1];
    const float* bq    = (const float*)d_in[2];
    const float* Wk    = (const float*)d_in[3];
    const float* bk    = (const float*)d_in[4];
    const float* Wv    = (const float*)d_in[5];
    const float* bv    = (const float*)d_in[6];
    const float* gamma = (const float*)d_in[7];

    float* out = (float*)d_out;
    float* atn = out + (size_t)NB * NCH * NTOK;

    _Float16* qkT  = (_Float16*)d_ws;                          // 2 MB
    _Float16* vbuf = qkT + (size_t)NB * NTOK * 64;             // 8 MB
    float* rs_inv  = (float*)(vbuf + (size_t)NB * NCH * NTOK); // 64 KB
    _Float16* W16  = (_Float16*)(rs_inv + NB * NTOK);          // 160 KB

    wpack_kernel<<<80, 256, 0, stream>>>(Wq, Wk, Wv, W16);
    qkv_mfma_kernel<<<512, 256, 0, stream>>>(x, W16, bq, bk, bv, qkT, vbuf);
    rowsum_kernel<<<256, 256, 0, stream>>>(qkT, rs_inv);
    attn_pv_kernel<<<256, 256, 0, stream>>>(qkT, vbuf, rs_inv, x, gamma, out, atn);
}

// Round 5
// 316.167 us; speedup vs baseline: 1.0557x; 1.0557x over previous
//
#include <hip/hip_runtime.h>

#define NB 4
#define NCH 256
#define NTOK 4096

typedef _Float16 f16x4 __attribute__((ext_vector_type(4)));
typedef _Float16 f16x8 __attribute__((ext_vector_type(8)));
typedef __fp16 h16x2 __attribute__((ext_vector_type(2)));
typedef float f32x4 __attribute__((ext_vector_type(4)));

union I4F16 { int i[4]; f16x8 v; };
union F2H  { h16x2 h; int i; };

// ---------------- K0: pack Wq/Wk/Wv -> fp16 [320][256] ----------------
__global__ __launch_bounds__(256) void wpack_kernel(
    const float* __restrict__ Wq, const float* __restrict__ Wk,
    const float* __restrict__ Wv, _Float16* __restrict__ W16)
{
    int g = blockIdx.x * 256 + threadIdx.x;       // 80 blocks -> 20480 quads
    if (g >= 320 * 64) return;
    int o = g >> 6, c4 = g & 63;
    const float* src = (o < 32) ? (Wq + o * NCH) :
                       (o < 64) ? (Wk + (o - 32) * NCH) : (Wv + (o - 64) * NCH);
    float4 v = ((const float4*)src)[c4];
    f16x4 p;
    p[0] = (_Float16)v.x; p[1] = (_Float16)v.y;
    p[2] = (_Float16)v.z; p[3] = (_Float16)v.w;
    *(f16x4*)(W16 + (size_t)o * NCH + c4 * 4) = p;
}

// ---------------- K1: QKV projection via MFMA ----------------
__global__ __launch_bounds__(256) void qkv_mfma_kernel(
    const float* __restrict__ x, const _Float16* __restrict__ W16,
    const float* __restrict__ bq, const float* __restrict__ bk,
    const float* __restrict__ bv,
    _Float16* __restrict__ qkT, _Float16* __restrict__ vbuf)
{
    __shared__ char xs[32 * 512];   // [n][c] f16, row 512B, swizzled
    const int tid = threadIdx.x;
    const int b = blockIdx.x & 3;
    const int n0 = (blockIdx.x >> 2) << 5;
    const float* xb = x + (size_t)b * NCH * NTOK + n0;

    {
        const int c4 = tid & 63, no = tid >> 6;
        #pragma unroll
        for (int u = 0; u < 4; ++u) {
            const int c = c4 * 4 + u;
            const float* xr = xb + (size_t)c * NTOK + no * 8;
            float4 a = *(const float4*)(xr);
            float4 bvec = *(const float4*)(xr + 4);
            float vals[8] = {a.x,a.y,a.z,a.w,bvec.x,bvec.y,bvec.z,bvec.w};
            #pragma unroll
            for (int j = 0; j < 8; ++j) {
                const int n = no * 8 + j;
                *(_Float16*)(xs + n * 512 + ((c * 2) ^ ((n & 7) << 4))) = (_Float16)vals[j];
            }
        }
    }
    __syncthreads();

    const int w = tid >> 6, l = tid & 63;
    const int iofs = l & 15, h = l >> 4;

    f32x4 acc[5][2];
    #pragma unroll
    for (int ot = 0; ot < 5; ++ot)
        #pragma unroll
        for (int nt = 0; nt < 2; ++nt) acc[ot][nt] = (f32x4){0.f,0.f,0.f,0.f};

    #pragma unroll
    for (int kk = 0; kk < 8; ++kk) {
        I4F16 bf[2];
        #pragma unroll
        for (int nt = 0; nt < 2; ++nt) {
            const int n = nt * 16 + iofs;
            bf[nt].v = *(const f16x8*)(xs + n * 512 + ((kk * 64 + h * 16) ^ ((n & 7) << 4)));
        }
        #pragma unroll
        for (int ot = 0; ot < 5; ++ot) {
            const int og = w * 5 + ot;
            f16x8 af = *(const f16x8*)(W16 + (size_t)(og * 16 + iofs) * NCH + kk * 32 + h * 8);
            #pragma unroll
            for (int nt = 0; nt < 2; ++nt)
                acc[ot][nt] = __builtin_amdgcn_mfma_f32_16x16x32_f16(af, bf[nt].v, acc[ot][nt], 0, 0, 0);
        }
    }

    #pragma unroll
    for (int ot = 0; ot < 5; ++ot) {
        const int og = w * 5 + ot;
        float4 bias;
        if (og < 2)      bias = *(const float4*)(bq + og * 16 + 4 * h);
        else if (og < 4) bias = *(const float4*)(bk + (og - 2) * 16 + 4 * h);
        else             bias = *(const float4*)(bv + (og - 4) * 16 + 4 * h);
        #pragma unroll
        for (int nt = 0; nt < 2; ++nt) {
            const int n = n0 + nt * 16 + iofs;
            f32x4 a = acc[ot][nt];
            if (og < 4) {
                f16x4 pk;
                pk[0] = (_Float16)(a[0] + bias.x); pk[1] = (_Float16)(a[1] + bias.y);
                pk[2] = (_Float16)(a[2] + bias.z); pk[3] = (_Float16)(a[3] + bias.w);
                const int col = (og < 2) ? (og * 16 + 4 * h) : (32 + (og - 2) * 16 + 4 * h);
                *(f16x4*)(qkT + (size_t)(b * NTOK + n) * 64 + col) = pk;
            } else {
                const int ob = (og - 4) * 16 + 4 * h;
                const float bb[4] = {bias.x, bias.y, bias.z, bias.w};
                #pragma unroll
                for (int r = 0; r < 4; ++r)
                    vbuf[(size_t)(b * NCH + ob + r) * NTOK + n] = (_Float16)(a[r] + bb[r]);
            }
        }
    }
}

// ---------------- K2: softmax row-sums (1/sum of exp(energy)) ----------------
__global__ __launch_bounds__(256) void rowsum_kernel(
    const _Float16* __restrict__ qkT, float* __restrict__ rs_inv)
{
    const int b = blockIdx.x >> 6;
    const int i0 = (blockIdx.x & 63) << 6;
    const int tid = threadIdx.x;
    const int w = tid >> 6, l = tid & 63;
    const int lrow = l & 15, lgrp = l >> 4;
    const _Float16* base = qkT + (size_t)b * NTOK * 64;

    f16x8 qfrag = *(const f16x8*)(base + (size_t)(i0 + w*16 + lrow) * 64 + lgrp * 8);
    float sums[4] = {0.f, 0.f, 0.f, 0.f};
    const f32x4 zero = {0.f, 0.f, 0.f, 0.f};
    #pragma unroll 4
    for (int j0 = 0; j0 < NTOK; j0 += 16) {
        f16x8 kfrag = *(const f16x8*)(base + (size_t)(j0 + lrow) * 64 + 32 + lgrp * 8);
        f32x4 s = __builtin_amdgcn_mfma_f32_16x16x32_f16(qfrag, kfrag, zero, 0, 0, 0);
        #pragma unroll
        for (int r = 0; r < 4; ++r) sums[r] += __expf(s[r]);
    }
    #pragma unroll
    for (int m = 1; m < 16; m <<= 1) {
        #pragma unroll
        for (int r = 0; r < 4; ++r) sums[r] += __shfl_xor(sums[r], m, 64);
    }
    if (lrow == 0) {
        #pragma unroll
        for (int r = 0; r < 4; ++r)
            rs_inv[b * NTOK + i0 + w*16 + lgrp*4 + r] = 1.0f / sums[r];
    }
}

// ---------------- K3: fused energy -> softmax -> attention write -> PV ----------------
// Barrier-free, LDS-free. Wave tile: 32 i x 32 c (fine-grained for occupancy).
// Grid 1024 = 4 blocks/CU -> 4 waves/SIMD. Attention j-interleaved across cs.
__global__ __launch_bounds__(256, 4) void attn_pv_kernel(
    const _Float16* __restrict__ qkT, const _Float16* __restrict__ vbuf,
    const float* __restrict__ rs_inv, const float* __restrict__ x,
    const float* __restrict__ gamma, float* __restrict__ out, float* __restrict__ atn)
{
    const int tid = threadIdx.x;
    const int w = tid >> 6, l = tid & 63;
    const int iofs = l & 15, h = l >> 4;
    // blockIdx decode: xcd-key = b*2+csh (L2 pinning), then (csl, i-tile-group)
    const int xk = blockIdx.x & 7, g = blockIdx.x >> 3;
    const int b = xk >> 1, csh = xk & 1;
    const int csl = g & 3, itb = g >> 2;
    const int cs = csh * 4 + csl;           // 0..7: 32-c slice AND attention j-eighth
    const int i0 = itb * 128 + w * 32;      // 32 i-rows per wave
    const int c0 = cs << 5;                 // 32-c slice

    const _Float16* qk_b = qkT + (size_t)b * NTOK * 64;
    const _Float16* v_b  = vbuf + (size_t)b * NCH * NTOK;
    float* atn_b = atn + (size_t)b * NTOK * NTOK;

    f16x8 qfrag[2];
    float rsl[2];
    #pragma unroll
    for (int ig = 0; ig < 2; ++ig) {
        qfrag[ig] = *(const f16x8*)(qk_b + (size_t)(i0 + ig*16 + iofs) * 64 + h * 8);
        rsl[ig] = __log2f(rs_inv[b * NTOK + i0 + ig*16 + iofs]);
    }

    const f32x4 zero = {0.f, 0.f, 0.f, 0.f};
    f32x4 acc[2][2];
    #pragma unroll
    for (int ig = 0; ig < 2; ++ig)
        #pragma unroll
        for (int ct = 0; ct < 2; ++ct) acc[ig][ct] = zero;

    const int srcA = ((l & 15) << 2) | ((l & 16) << 3);
    const int srcB = srcA + 64;
    const bool hi = (l >= 32);
    const float LOG2E = 1.44269504f;

    for (int j0 = 0; j0 < NTOK; j0 += 32) {
        const bool writeA = (((j0 >> 5) & 7) == cs);
        f16x8 kfrag[2];
        #pragma unroll
        for (int t = 0; t < 2; ++t)
            kfrag[t] = *(const f16x8*)(qk_b + (size_t)(j0 + t*16 + iofs) * 64 + 32 + h * 8);

        I4F16 bfrag[2];
        #pragma unroll
        for (int ig = 0; ig < 2; ++ig) {
            int dw[2][2];
            #pragma unroll
            for (int t = 0; t < 2; ++t) {
                f32x4 s = __builtin_amdgcn_mfma_f32_16x16x32_f16(kfrag[t], qfrag[ig], zero, 0, 0, 0);
                float pvf[4];
                #pragma unroll
                for (int r = 0; r < 4; ++r)
                    pvf[r] = __builtin_amdgcn_exp2f(__builtin_fmaf(s[r], LOG2E, rsl[ig]));
                if (writeA) {
                    float4 st = {pvf[0], pvf[1], pvf[2], pvf[3]};
                    *(float4*)(atn_b + (size_t)(i0 + ig*16 + iofs) * NTOK + j0 + t*16 + h*4) = st;
                }
                F2H p0, p1;
                p0.h = __builtin_amdgcn_cvt_pkrtz(pvf[0], pvf[1]);
                p1.h = __builtin_amdgcn_cvt_pkrtz(pvf[2], pvf[3]);
                dw[t][0] = p0.i; dw[t][1] = p1.i;
            }
            int a0 = __builtin_amdgcn_ds_bpermute(srcA, dw[0][0]);
            int a1 = __builtin_amdgcn_ds_bpermute(srcA, dw[1][0]);
            int b0 = __builtin_amdgcn_ds_bpermute(srcA, dw[0][1]);
            int b1 = __builtin_amdgcn_ds_bpermute(srcA, dw[1][1]);
            int c0_ = __builtin_amdgcn_ds_bpermute(srcB, dw[0][0]);
            int c1_ = __builtin_amdgcn_ds_bpermute(srcB, dw[1][0]);
            int d0 = __builtin_amdgcn_ds_bpermute(srcB, dw[0][1]);
            int d1 = __builtin_amdgcn_ds_bpermute(srcB, dw[1][1]);
            bfrag[ig].i[0] = hi ? a1 : a0;
            bfrag[ig].i[1] = hi ? b1 : b0;
            bfrag[ig].i[2] = hi ? c1_ : c0_;
            bfrag[ig].i[3] = hi ? d1 : d0;
        }
        #pragma unroll
        for (int ct = 0; ct < 2; ++ct) {
            f16x8 vfrag = *(const f16x8*)(v_b + (size_t)(c0 + ct*16 + iofs) * NTOK + j0 + h * 8);
            #pragma unroll
            for (int ig = 0; ig < 2; ++ig)
                acc[ig][ct] = __builtin_amdgcn_mfma_f32_16x16x32_f16(vfrag, bfrag[ig].v, acc[ig][ct], 0, 0, 0);
        }
    }

    // epilogue: out[b][c][i] = gamma*acc + x. D: row c-off = 4h+r, col i = iofs
    const float g2 = gamma[0];
    #pragma unroll
    for (int ig = 0; ig < 2; ++ig) {
        #pragma unroll
        for (int ct = 0; ct < 2; ++ct) {
            #pragma unroll
            for (int r = 0; r < 4; ++r) {
                const int c = c0 + ct*16 + 4*h + r;
                const size_t bse = ((size_t)(b * NCH + c)) * NTOK + i0 + ig*16 + iofs;
                out[bse] = g2 * acc[ig][ct][r] + x[bse];
            }
        }
    }
}

extern "C" void kernel_launch(void* const* d_in, const int* in_sizes, int n_in,
                              void* d_out, int out_size, void* d_ws, size_t ws_size,
                              hipStream_t stream) {
    const float* x     = (const float*)d_in[0];
    const float* Wq    = (const float*)d_in[1];
    const float* bq    = (const float*)d_in[2];
    const float* Wk    = (const float*)d_in[3];
    const float* bk    = (const float*)d_in[4];
    const float* Wv    = (const float*)d_in[5];
    const float* bv    = (const float*)d_in[6];
    const float* gamma = (const float*)d_in[7];

    float* out = (float*)d_out;
    float* atn = out + (size_t)NB * NCH * NTOK;

    _Float16* qkT  = (_Float16*)d_ws;                          // 2 MB
    _Float16* vbuf = qkT + (size_t)NB * NTOK * 64;             // 8 MB
    float* rs_inv  = (float*)(vbuf + (size_t)NB * NCH * NTOK); // 64 KB
    _Float16* W16  = (_Float16*)(rs_inv + NB * NTOK);          // 160 KB

    wpack_kernel<<<80, 256, 0, stream>>>(Wq, Wk, Wv, W16);
    qkv_mfma_kernel<<<512, 256, 0, stream>>>(x, W16, bq, bk, bv, qkT, vbuf);
    rowsum_kernel<<<256, 256, 0, stream>>>(qkT, rs_inv);
    attn_pv_kernel<<<1024, 256, 0, stream>>>(qkT, vbuf, rs_inv, x, gamma, out, atn);
}

// Round 6
// 214.066 us; speedup vs baseline: 1.5592x; 1.4770x over previous
//
#include <hip/hip_runtime.h>

#define NB 4
#define NCH 256
#define NTOK 4096

typedef _Float16 f16x4 __attribute__((ext_vector_type(4)));
typedef _Float16 f16x8 __attribute__((ext_vector_type(8)));
typedef __fp16 h16x2 __attribute__((ext_vector_type(2)));
typedef float f32x4 __attribute__((ext_vector_type(4)));

union F2H  { h16x2 h; int i; };
union U64  { uint2 u; f16x4 h; int2 i2; };

// ---------------- K0: pack Wq/Wk/Wv -> fp16 [320][256] ----------------
__global__ __launch_bounds__(256) void wpack_kernel(
    const float* __restrict__ Wq, const float* __restrict__ Wk,
    const float* __restrict__ Wv, _Float16* __restrict__ W16)
{
    int g = blockIdx.x * 256 + threadIdx.x;
    if (g >= 320 * 64) return;
    int o = g >> 6, c4 = g & 63;
    const float* src = (o < 32) ? (Wq + o * NCH) :
                       (o < 64) ? (Wk + (o - 32) * NCH) : (Wv + (o - 64) * NCH);
    float4 v = ((const float4*)src)[c4];
    f16x4 p;
    p[0] = (_Float16)v.x; p[1] = (_Float16)v.y;
    p[2] = (_Float16)v.z; p[3] = (_Float16)v.w;
    *(f16x4*)(W16 + (size_t)o * NCH + c4 * 4) = p;
}

// ---------------- K1: QKV projection via MFMA ----------------
__global__ __launch_bounds__(256) void qkv_mfma_kernel(
    const float* __restrict__ x, const _Float16* __restrict__ W16,
    const float* __restrict__ bq, const float* __restrict__ bk,
    const float* __restrict__ bv,
    _Float16* __restrict__ qkT, _Float16* __restrict__ vbuf)
{
    __shared__ char xs[32 * 512];   // [n][c] f16, row 512B, swizzled
    const int tid = threadIdx.x;
    const int b = blockIdx.x & 3;
    const int n0 = (blockIdx.x >> 2) << 5;
    const float* xb = x + (size_t)b * NCH * NTOK + n0;

    {
        const int c4 = tid & 63, no = tid >> 6;
        #pragma unroll
        for (int u = 0; u < 4; ++u) {
            const int c = c4 * 4 + u;
            const float* xr = xb + (size_t)c * NTOK + no * 8;
            float4 a = *(const float4*)(xr);
            float4 bvec = *(const float4*)(xr + 4);
            float vals[8] = {a.x,a.y,a.z,a.w,bvec.x,bvec.y,bvec.z,bvec.w};
            #pragma unroll
            for (int j = 0; j < 8; ++j) {
                const int n = no * 8 + j;
                *(_Float16*)(xs + n * 512 + ((c * 2) ^ ((n & 7) << 4))) = (_Float16)vals[j];
            }
        }
    }
    __syncthreads();

    const int w = tid >> 6, l = tid & 63;
    const int iofs = l & 15, h = l >> 4;

    f32x4 acc[5][2];
    #pragma unroll
    for (int ot = 0; ot < 5; ++ot)
        #pragma unroll
        for (int nt = 0; nt < 2; ++nt) acc[ot][nt] = (f32x4){0.f,0.f,0.f,0.f};

    #pragma unroll
    for (int kk = 0; kk < 8; ++kk) {
        f16x8 bf[2];
        #pragma unroll
        for (int nt = 0; nt < 2; ++nt) {
            const int n = nt * 16 + iofs;
            bf[nt] = *(const f16x8*)(xs + n * 512 + ((kk * 64 + h * 16) ^ ((n & 7) << 4)));
        }
        #pragma unroll
        for (int ot = 0; ot < 5; ++ot) {
            const int og = w * 5 + ot;
            f16x8 af = *(const f16x8*)(W16 + (size_t)(og * 16 + iofs) * NCH + kk * 32 + h * 8);
            #pragma unroll
            for (int nt = 0; nt < 2; ++nt)
                acc[ot][nt] = __builtin_amdgcn_mfma_f32_16x16x32_f16(af, bf[nt], acc[ot][nt], 0, 0, 0);
        }
    }

    #pragma unroll
    for (int ot = 0; ot < 5; ++ot) {
        const int og = w * 5 + ot;
        float4 bias;
        if (og < 2)      bias = *(const float4*)(bq + og * 16 + 4 * h);
        else if (og < 4) bias = *(const float4*)(bk + (og - 2) * 16 + 4 * h);
        else             bias = *(const float4*)(bv + (og - 4) * 16 + 4 * h);
        #pragma unroll
        for (int nt = 0; nt < 2; ++nt) {
            const int n = n0 + nt * 16 + iofs;
            f32x4 a = acc[ot][nt];
            if (og < 4) {
                f16x4 pk;
                pk[0] = (_Float16)(a[0] + bias.x); pk[1] = (_Float16)(a[1] + bias.y);
                pk[2] = (_Float16)(a[2] + bias.z); pk[3] = (_Float16)(a[3] + bias.w);
                const int col = (og < 2) ? (og * 16 + 4 * h) : (32 + (og - 2) * 16 + 4 * h);
                *(f16x4*)(qkT + (size_t)(b * NTOK + n) * 64 + col) = pk;
            } else {
                const int ob = (og - 4) * 16 + 4 * h;
                const float bb[4] = {bias.x, bias.y, bias.z, bias.w};
                #pragma unroll
                for (int r = 0; r < 4; ++r)
                    vbuf[(size_t)(b * NCH + ob + r) * NTOK + n] = (_Float16)(a[r] + bb[r]);
            }
        }
    }
}

// ---------------- K2: softmax row-sums (atomic partial sums) ----------------
// grid 1024: (b, 64-i block, 1024-j quarter). Wave: 16 i x 1024 j.
__global__ __launch_bounds__(256) void rowsum_kernel(
    const _Float16* __restrict__ qkT, float* __restrict__ rs_sum)
{
    const int bid = blockIdx.x;
    const int b = bid >> 8;                 // 0..3
    const int rem = bid & 255;
    const int ib = rem >> 2, js = rem & 3;  // 64 i-blocks x 4 j-quarters
    const int tid = threadIdx.x;
    const int w = tid >> 6, l = tid & 63;
    const int iofs = l & 15, h = l >> 4;
    const int i16 = ib * 64 + w * 16;
    const int j0 = js * 1024;
    const _Float16* qk_b = qkT + (size_t)b * NTOK * 64;

    // B-operand: col i, k = d
    f16x8 qfrag = *(const f16x8*)(qk_b + (size_t)(i16 + iofs) * 64 + h * 8);
    float sums[4] = {0.f, 0.f, 0.f, 0.f};
    const f32x4 zero = {0.f, 0.f, 0.f, 0.f};
    #pragma unroll 4
    for (int jt = 0; jt < 64; ++jt) {
        // A-operand: rows j, k = d
        f16x8 kfrag = *(const f16x8*)(qk_b + (size_t)(j0 + jt*16 + iofs) * 64 + 32 + h * 8);
        f32x4 s = __builtin_amdgcn_mfma_f32_16x16x32_f16(kfrag, qfrag, zero, 0, 0, 0);
        #pragma unroll
        for (int r = 0; r < 4; ++r) sums[r] += __expf(s[r]);
    }
    float tot = sums[0] + sums[1] + sums[2] + sums[3];
    tot += __shfl_xor(tot, 16, 64);
    tot += __shfl_xor(tot, 32, 64);
    if (l < 16) atomicAdd(&rs_sum[b * NTOK + i16 + iofs], tot);
}

// ---------------- K3: flash-style fused energy->softmax->attn-write->PV ----------------
// Block: (b, 32 i-rows) x all 256 c. 4 waves. LDS P dbuf 2x[32][512] f16 (64KB).
// Phase A: waves j-split compute S^T chunk, exp (normalized), -> LDS.
// Phase B: attn write from LDS (coalesced) + PV GEMM (wave owns 64 c).
__global__ __launch_bounds__(256, 2) void attn_pv_kernel(
    const _Float16* __restrict__ qkT, const _Float16* __restrict__ vbuf,
    const float* __restrict__ rs_sum, const float* __restrict__ x,
    const float* __restrict__ gamma, float* __restrict__ out, float* __restrict__ atn)
{
    __shared__ char P[2][32 * 1024];
    const int tid = threadIdx.x;
    const int w = tid >> 6, l = tid & 63;
    const int iofs = l & 15, h = l >> 4;
    // XCD pinning: blockIdx&7 -> (b, itb low bit); XCD x serves batch x>>1
    const int xk = blockIdx.x & 7, rest = blockIdx.x >> 3;
    const int b = xk >> 1;
    const int itb = (rest << 1) | (xk & 1);   // 0..127
    const int i0 = itb << 5;

    const _Float16* qk_b = qkT + (size_t)b * NTOK * 64;
    const _Float16* v_b  = vbuf + (size_t)b * NCH * NTOK;
    float* atn_b = atn + (size_t)b * NTOK * NTOK;
    const int c0w = w * 64;
    const float LOG2E = 1.44269504f;

    // Phase-A per-wave constants: q B-frags for the block's two 16-i tiles
    f16x8 qfrag[2];
    float rsl[2];
    #pragma unroll
    for (int ig = 0; ig < 2; ++ig) {
        qfrag[ig] = *(const f16x8*)(qk_b + (size_t)(i0 + ig*16 + iofs) * 64 + h * 8);
        rsl[ig] = -__log2f(rs_sum[b * NTOK + i0 + ig*16 + iofs]);
    }

    const f32x4 zero = {0.f, 0.f, 0.f, 0.f};
    f32x4 acc[2][4];
    #pragma unroll
    for (int ig = 0; ig < 2; ++ig)
        #pragma unroll
        for (int ct = 0; ct < 4; ++ct) acc[ig][ct] = zero;

    // ---- phase A: compute S^T for j-range [cj0 + w*128, +128), exp -> LDS buf ----
    auto phaseA = [&](int chunk, int buf) {
        const int jbase = chunk * 512 + w * 128;
        #pragma unroll
        for (int jt = 0; jt < 8; ++jt) {
            const int jg = jbase + jt * 16;
            // A-operand: k rows j, k-dim = d
            f16x8 kfrag = *(const f16x8*)(qk_b + (size_t)(jg + iofs) * 64 + 32 + h * 8);
            #pragma unroll
            for (int ig = 0; ig < 2; ++ig) {
                f32x4 s = __builtin_amdgcn_mfma_f32_16x16x32_f16(kfrag, qfrag[ig], zero, 0, 0, 0);
                float pvf[4];
                #pragma unroll
                for (int r = 0; r < 4; ++r)
                    pvf[r] = __builtin_amdgcn_exp2f(__builtin_fmaf(s[r], LOG2E, rsl[ig]));
                F2H p0, p1;
                p0.h = __builtin_amdgcn_cvt_pkrtz(pvf[0], pvf[1]);
                p1.h = __builtin_amdgcn_cvt_pkrtz(pvf[2], pvf[3]);
                const int iloc = ig * 16 + iofs;
                const int jloc = w * 128 + jt * 16 + 4 * h;   // 4 consecutive j
                const int byte = iloc * 1024 + ((jloc * 2) ^ ((iloc & 7) << 4));
                U64 u; u.i2.x = p0.i; u.i2.y = p1.i;
                *(int2*)(P[buf] + byte) = u.i2;
            }
        }
    };

    // ---- phase B: attn write from LDS + PV GEMM over the chunk ----
    auto phaseB = [&](int chunk, int buf) {
        const int cj0 = chunk * 512;
        // B1: coalesced attention write. 2 passes x (16 i-rows x 16 lanes/row)
        {
            const int g16 = tid >> 4, lane16 = tid & 15;
            #pragma unroll
            for (int p = 0; p < 2; ++p) {
                const int iloc = p * 16 + g16;
                float* arow = atn_b + (size_t)(i0 + iloc) * NTOK + cj0;
                const int sw = (iloc & 7) << 4;
                #pragma unroll
                for (int u = 0; u < 8; ++u) {
                    const int jl = u * 64 + lane16 * 4;
                    U64 v; v.i2 = *(const int2*)(P[buf] + iloc * 1024 + ((jl * 2) ^ sw));
                    float4 st = {(float)v.h[0], (float)v.h[1], (float)v.h[2], (float)v.h[3]};
                    *(float4*)(arow + jl) = st;
                }
            }
        }
        // B2: PV. wave owns c-range [c0w, +64): 4 c-tiles x 2 i-tiles, K=512
        #pragma unroll 4
        for (int ks = 0; ks < 16; ++ks) {
            f16x8 pfrag[2];
            #pragma unroll
            for (int ig = 0; ig < 2; ++ig) {
                const int iloc = ig * 16 + iofs;
                const int byte = iloc * 1024 + ((ks * 64 + h * 16) ^ ((iloc & 7) << 4));
                pfrag[ig] = *(const f16x8*)(P[buf] + byte);
            }
            const int jg = cj0 + ks * 32 + h * 8;
            #pragma unroll
            for (int ct = 0; ct < 4; ++ct) {
                f16x8 vfrag = *(const f16x8*)(v_b + (size_t)(c0w + ct*16 + iofs) * NTOK + jg);
                #pragma unroll
                for (int ig = 0; ig < 2; ++ig)
                    acc[ig][ct] = __builtin_amdgcn_mfma_f32_16x16x32_f16(vfrag, pfrag[ig], acc[ig][ct], 0, 0, 0);
            }
        }
    };

    phaseA(0, 0);
    __syncthreads();
    for (int c = 0; c < 8; ++c) {
        if (c < 7) phaseA(c + 1, (c + 1) & 1);
        phaseB(c, c & 1);
        __syncthreads();
    }

    // epilogue: out[b][c][i] = gamma*acc + x
    const float g2 = gamma[0];
    #pragma unroll
    for (int ig = 0; ig < 2; ++ig) {
        #pragma unroll
        for (int ct = 0; ct < 4; ++ct) {
            #pragma unroll
            for (int r = 0; r < 4; ++r) {
                const int c = c0w + ct*16 + 4*h + r;
                const size_t bse = ((size_t)(b * NCH + c)) * NTOK + i0 + ig*16 + iofs;
                out[bse] = g2 * acc[ig][ct][r] + x[bse];
            }
        }
    }
}

extern "C" void kernel_launch(void* const* d_in, const int* in_sizes, int n_in,
                              void* d_out, int out_size, void* d_ws, size_t ws_size,
                              hipStream_t stream) {
    const float* x     = (const float*)d_in[0];
    const float* Wq    = (const float*)d_in[1];
    const float* bq    = (const float*)d_in[2];
    const float* Wk    = (const float*)d_in[3];
    const float* bk    = (const float*)d_in[4];
    const float* Wv    = (const float*)d_in[5];
    const float* bv    = (const float*)d_in[6];
    const float* gamma = (const float*)d_in[7];

    float* out = (float*)d_out;
    float* atn = out + (size_t)NB * NCH * NTOK;

    _Float16* qkT  = (_Float16*)d_ws;                          // 2 MB
    _Float16* vbuf = qkT + (size_t)NB * NTOK * 64;             // 8 MB
    float* rs_sum  = (float*)(vbuf + (size_t)NB * NCH * NTOK); // 64 KB
    _Float16* W16  = (_Float16*)(rs_sum + NB * NTOK);          // 160 KB

    wpack_kernel<<<80, 256, 0, stream>>>(Wq, Wk, Wv, W16);
    qkv_mfma_kernel<<<512, 256, 0, stream>>>(x, W16, bq, bk, bv, qkT, vbuf);
    hipMemsetAsync(rs_sum, 0, (size_t)NB * NTOK * sizeof(float), stream);
    rowsum_kernel<<<1024, 256, 0, stream>>>(qkT, rs_sum);
    attn_pv_kernel<<<512, 256, 0, stream>>>(qkT, vbuf, rs_sum, x, gamma, out, atn);
}

// Round 8
// 204.652 us; speedup vs baseline: 1.6310x; 1.0460x over previous
//
#include <hip/hip_runtime.h>

#define NB 4
#define NCH 256
#define NTOK 4096

typedef _Float16 f16x4 __attribute__((ext_vector_type(4)));
typedef _Float16 f16x8 __attribute__((ext_vector_type(8)));
typedef __fp16 h16x2 __attribute__((ext_vector_type(2)));
typedef float f32x4 __attribute__((ext_vector_type(4)));

union F2H  { h16x2 h; int i; };
union U64  { uint2 u; f16x4 h; int2 i2; };

// LDS-only barrier: do NOT drain vmcnt (attention stores stay in flight).
#define LDS_BARRIER() asm volatile("s_waitcnt lgkmcnt(0)\n\ts_barrier" ::: "memory")

// ---------------- K0: pack Wq/Wk/Wv -> fp16 [320][256] ----------------
__global__ __launch_bounds__(256) void wpack_kernel(
    const float* __restrict__ Wq, const float* __restrict__ Wk,
    const float* __restrict__ Wv, _Float16* __restrict__ W16)
{
    int g = blockIdx.x * 256 + threadIdx.x;
    if (g >= 320 * 64) return;
    int o = g >> 6, c4 = g & 63;
    const float* src = (o < 32) ? (Wq + o * NCH) :
                       (o < 64) ? (Wk + (o - 32) * NCH) : (Wv + (o - 64) * NCH);
    float4 v = ((const float4*)src)[c4];
    f16x4 p;
    p[0] = (_Float16)v.x; p[1] = (_Float16)v.y;
    p[2] = (_Float16)v.z; p[3] = (_Float16)v.w;
    *(f16x4*)(W16 + (size_t)o * NCH + c4 * 4) = p;
}

// ---------------- K1: QKV projection via MFMA ----------------
__global__ __launch_bounds__(256) void qkv_mfma_kernel(
    const float* __restrict__ x, const _Float16* __restrict__ W16,
    const float* __restrict__ bq, const float* __restrict__ bk,
    const float* __restrict__ bv,
    _Float16* __restrict__ qkT, _Float16* __restrict__ vbuf)
{
    __shared__ char xs[32 * 512];   // [n][c] f16, row 512B, swizzled
    const int tid = threadIdx.x;
    const int b = blockIdx.x & 3;
    const int n0 = (blockIdx.x >> 2) << 5;
    const float* xb = x + (size_t)b * NCH * NTOK + n0;

    {
        const int c4 = tid & 63, no = tid >> 6;
        #pragma unroll
        for (int u = 0; u < 4; ++u) {
            const int c = c4 * 4 + u;
            const float* xr = xb + (size_t)c * NTOK + no * 8;
            float4 a = *(const float4*)(xr);
            float4 bvec = *(const float4*)(xr + 4);
            float vals[8] = {a.x,a.y,a.z,a.w,bvec.x,bvec.y,bvec.z,bvec.w};
            #pragma unroll
            for (int j = 0; j < 8; ++j) {
                const int n = no * 8 + j;
                *(_Float16*)(xs + n * 512 + ((c * 2) ^ ((n & 7) << 4))) = (_Float16)vals[j];
            }
        }
    }
    __syncthreads();

    const int w = tid >> 6, l = tid & 63;
    const int iofs = l & 15, h = l >> 4;

    f32x4 acc[5][2];
    #pragma unroll
    for (int ot = 0; ot < 5; ++ot)
        #pragma unroll
        for (int nt = 0; nt < 2; ++nt) acc[ot][nt] = (f32x4){0.f,0.f,0.f,0.f};

    #pragma unroll
    for (int kk = 0; kk < 8; ++kk) {
        f16x8 bf[2];
        #pragma unroll
        for (int nt = 0; nt < 2; ++nt) {
            const int n = nt * 16 + iofs;
            bf[nt] = *(const f16x8*)(xs + n * 512 + ((kk * 64 + h * 16) ^ ((n & 7) << 4)));
        }
        #pragma unroll
        for (int ot = 0; ot < 5; ++ot) {
            const int og = w * 5 + ot;
            f16x8 af = *(const f16x8*)(W16 + (size_t)(og * 16 + iofs) * NCH + kk * 32 + h * 8);
            #pragma unroll
            for (int nt = 0; nt < 2; ++nt)
                acc[ot][nt] = __builtin_amdgcn_mfma_f32_16x16x32_f16(af, bf[nt], acc[ot][nt], 0, 0, 0);
        }
    }

    #pragma unroll
    for (int ot = 0; ot < 5; ++ot) {
        const int og = w * 5 + ot;
        float4 bias;
        if (og < 2)      bias = *(const float4*)(bq + og * 16 + 4 * h);
        else if (og < 4) bias = *(const float4*)(bk + (og - 2) * 16 + 4 * h);
        else             bias = *(const float4*)(bv + (og - 4) * 16 + 4 * h);
        #pragma unroll
        for (int nt = 0; nt < 2; ++nt) {
            const int n = n0 + nt * 16 + iofs;
            f32x4 a = acc[ot][nt];
            if (og < 4) {
                f16x4 pk;
                pk[0] = (_Float16)(a[0] + bias.x); pk[1] = (_Float16)(a[1] + bias.y);
                pk[2] = (_Float16)(a[2] + bias.z); pk[3] = (_Float16)(a[3] + bias.w);
                const int col = (og < 2) ? (og * 16 + 4 * h) : (32 + (og - 2) * 16 + 4 * h);
                *(f16x4*)(qkT + (size_t)(b * NTOK + n) * 64 + col) = pk;
            } else {
                const int ob = (og - 4) * 16 + 4 * h;
                const float bb[4] = {bias.x, bias.y, bias.z, bias.w};
                #pragma unroll
                for (int r = 0; r < 4; ++r)
                    vbuf[(size_t)(b * NCH + ob + r) * NTOK + n] = (_Float16)(a[r] + bb[r]);
            }
        }
    }
}

// ---------------- K2: softmax row-sums (atomic partial sums) ----------------
__global__ __launch_bounds__(256) void rowsum_kernel(
    const _Float16* __restrict__ qkT, float* __restrict__ rs_sum)
{
    const int bid = blockIdx.x;
    const int b = bid >> 8;
    const int rem = bid & 255;
    const int ib = rem >> 2, js = rem & 3;
    const int tid = threadIdx.x;
    const int w = tid >> 6, l = tid & 63;
    const int iofs = l & 15, h = l >> 4;
    const int i16 = ib * 64 + w * 16;
    const int j0 = js * 1024;
    const _Float16* qk_b = qkT + (size_t)b * NTOK * 64;

    f16x8 qfrag = *(const f16x8*)(qk_b + (size_t)(i16 + iofs) * 64 + h * 8);
    float sums[4] = {0.f, 0.f, 0.f, 0.f};
    const f32x4 zero = {0.f, 0.f, 0.f, 0.f};
    #pragma unroll 4
    for (int jt = 0; jt < 64; ++jt) {
        f16x8 kfrag = *(const f16x8*)(qk_b + (size_t)(j0 + jt*16 + iofs) * 64 + 32 + h * 8);
        f32x4 s = __builtin_amdgcn_mfma_f32_16x16x32_f16(kfrag, qfrag, zero, 0, 0, 0);
        #pragma unroll
        for (int r = 0; r < 4; ++r) sums[r] += __expf(s[r]);
    }
    float tot = sums[0] + sums[1] + sums[2] + sums[3];
    tot += __shfl_xor(tot, 16, 64);
    tot += __shfl_xor(tot, 32, 64);
    if (l < 16) atomicAdd(&rs_sum[b * NTOK + i16 + iofs], tot);
}

// ---------------- K3: flash-style fused energy->softmax->attn-write->PV ----------------
// Block: (b, 32 i-rows) x all 256 c. 8 waves (512 thr), chunk = 256 j.
// LDS P dbuf 2x[32][256] f16 = 32KB -> 2 blocks/CU = 16 waves/CU = 4/SIMD.
// Barriers are LDS-only (no vmcnt drain): attention stores stay in flight.
__global__ __launch_bounds__(512, 4) void attn_pv_kernel(
    const _Float16* __restrict__ qkT, const _Float16* __restrict__ vbuf,
    const float* __restrict__ rs_sum, const float* __restrict__ x,
    const float* __restrict__ gamma, float* __restrict__ out, float* __restrict__ atn)
{
    __shared__ char P[2][32 * 512];
    const int tid = threadIdx.x;
    const int w = tid >> 6, l = tid & 63;   // w: 0..7
    const int iofs = l & 15, h = l >> 4;
    const int xk = blockIdx.x & 7, rest = blockIdx.x >> 3;   // grid 512
    const int b = xk >> 1;
    const int itb = (rest << 1) | (xk & 1);   // 0..127
    const int i0 = itb << 5;                  // 32 i-rows per block

    const _Float16* qk_b = qkT + (size_t)b * NTOK * 64;
    const _Float16* v_b  = vbuf + (size_t)b * NCH * NTOK;
    float* atn_b = atn + (size_t)b * NTOK * NTOK;
    const int c0w = w * 32;                   // wave owns 32 c
    const float LOG2E = 1.44269504f;

    f16x8 qfrag[2];
    float rsl[2];
    #pragma unroll
    for (int ig = 0; ig < 2; ++ig) {
        qfrag[ig] = *(const f16x8*)(qk_b + (size_t)(i0 + ig*16 + iofs) * 64 + h * 8);
        rsl[ig] = -__log2f(rs_sum[b * NTOK + i0 + ig*16 + iofs]);
    }

    const f32x4 zero = {0.f, 0.f, 0.f, 0.f};
    f32x4 acc[2][2];
    #pragma unroll
    for (int ig = 0; ig < 2; ++ig)
        #pragma unroll
        for (int ct = 0; ct < 2; ++ct) acc[ig][ct] = zero;

    // phase A: wave w computes S^T for j in [chunk*256 + w*32, +32), exp -> LDS
    auto phaseA = [&](int chunk, int buf) {
        const int jbase = chunk * 256 + w * 32;
        #pragma unroll
        for (int jt = 0; jt < 2; ++jt) {
            const int jg = jbase + jt * 16;
            f16x8 kfrag = *(const f16x8*)(qk_b + (size_t)(jg + iofs) * 64 + 32 + h * 8);
            #pragma unroll
            for (int ig = 0; ig < 2; ++ig) {
                f32x4 s = __builtin_amdgcn_mfma_f32_16x16x32_f16(kfrag, qfrag[ig], zero, 0, 0, 0);
                float pvf[4];
                #pragma unroll
                for (int r = 0; r < 4; ++r)
                    pvf[r] = __builtin_amdgcn_exp2f(__builtin_fmaf(s[r], LOG2E, rsl[ig]));
                F2H p0, p1;
                p0.h = __builtin_amdgcn_cvt_pkrtz(pvf[0], pvf[1]);
                p1.h = __builtin_amdgcn_cvt_pkrtz(pvf[2], pvf[3]);
                const int iloc = ig * 16 + iofs;
                const int jloc = w * 32 + jt * 16 + 4 * h;
                const int byte = iloc * 512 + ((jloc * 2) ^ ((iloc & 7) << 4));
                U64 u; u.i2.x = p0.i; u.i2.y = p1.i;
                *(int2*)(P[buf] + byte) = u.i2;
            }
        }
    };

    // phase B: attention write from LDS (coalesced) + PV GEMM over the chunk
    auto phaseB = [&](int chunk, int buf) {
        const int cj0 = chunk * 256;
        {   // B1: 512 threads cover 32 rows x 256 j
            const int g16 = tid >> 4, lane16 = tid & 15;   // g16: 0..31 = row
            float* arow = atn_b + (size_t)(i0 + g16) * NTOK + cj0;
            const int sw = (g16 & 7) << 4;
            #pragma unroll
            for (int u = 0; u < 4; ++u) {
                const int jl = u * 64 + lane16 * 4;
                U64 v; v.i2 = *(const int2*)(P[buf] + g16 * 512 + ((jl * 2) ^ sw));
                float4 st = {(float)v.h[0], (float)v.h[1], (float)v.h[2], (float)v.h[3]};
                *(float4*)(arow + jl) = st;
            }
        }
        // B2: PV. wave owns c-range [c0w, +32): 2 c-tiles x 2 i-tiles, K=256
        #pragma unroll 4
        for (int ks = 0; ks < 8; ++ks) {
            f16x8 pfrag[2];
            #pragma unroll
            for (int ig = 0; ig < 2; ++ig) {
                const int iloc = ig * 16 + iofs;
                const int byte = iloc * 512 + ((ks * 64 + h * 16) ^ ((iloc & 7) << 4));
                pfrag[ig] = *(const f16x8*)(P[buf] + byte);
            }
            const int jg = cj0 + ks * 32 + h * 8;
            #pragma unroll
            for (int ct = 0; ct < 2; ++ct) {
                f16x8 vfrag = *(const f16x8*)(v_b + (size_t)(c0w + ct*16 + iofs) * NTOK + jg);
                #pragma unroll
                for (int ig = 0; ig < 2; ++ig)
                    acc[ig][ct] = __builtin_amdgcn_mfma_f32_16x16x32_f16(vfrag, pfrag[ig], acc[ig][ct], 0, 0, 0);
            }
        }
    };

    phaseA(0, 0);
    LDS_BARRIER();
    for (int c = 0; c < 16; ++c) {
        if (c < 15) phaseA(c + 1, (c + 1) & 1);
        phaseB(c, c & 1);
        LDS_BARRIER();
    }

    // epilogue: out[b][c][i] = gamma*acc + x
    const float g2 = gamma[0];
    #pragma unroll
    for (int ig = 0; ig < 2; ++ig) {
        #pragma unroll
        for (int ct = 0; ct < 2; ++ct) {
            #pragma unroll
            for (int r = 0; r < 4; ++r) {
                const int c = c0w + ct*16 + 4*h + r;
                const size_t bse = ((size_t)(b * NCH + c)) * NTOK + i0 + ig*16 + iofs;
                out[bse] = g2 * acc[ig][ct][r] + x[bse];
            }
        }
    }
}

extern "C" void kernel_launch(void* const* d_in, const int* in_sizes, int n_in,
                              void* d_out, int out_size, void* d_ws, size_t ws_size,
                              hipStream_t stream) {
    const float* x     = (const float*)d_in[0];
    const float* Wq    = (const float*)d_in[1];
    const float* bq    = (const float*)d_in[2];
    const float* Wk    = (const float*)d_in[3];
    const float* bk    = (const float*)d_in[4];
    const float* Wv    = (const float*)d_in[5];
    const float* bv    = (const float*)d_in[6];
    const float* gamma = (const float*)d_in[7];

    float* out = (float*)d_out;
    float* atn = out + (size_t)NB * NCH * NTOK;

    _Float16* qkT  = (_Float16*)d_ws;                          // 2 MB
    _Float16* vbuf = qkT + (size_t)NB * NTOK * 64;             // 8 MB
    float* rs_sum  = (float*)(vbuf + (size_t)NB * NCH * NTOK); // 64 KB
    _Float16* W16  = (_Float16*)(rs_sum + NB * NTOK);          // 160 KB

    wpack_kernel<<<80, 256, 0, stream>>>(Wq, Wk, Wv, W16);
    qkv_mfma_kernel<<<512, 256, 0, stream>>>(x, W16, bq, bk, bv, qkT, vbuf);
    hipMemsetAsync(rs_sum, 0, (size_t)NB * NTOK * sizeof(float), stream);
    rowsum_kernel<<<1024, 256, 0, stream>>>(qkT, rs_sum);
    attn_pv_kernel<<<512, 512, 0, stream>>>(qkT, vbuf, rs_sum, x, gamma, out, atn);
}